// Round 3
// baseline (416.744 us; speedup 1.0000x reference)
//
#include <hip/hip_runtime.h>

// AttentionActorCritic fused forward, MI355X (gfx950).
// Round 3: wave-ownership design. 16 samples/block, 576 threads (9 waves = 9
// M-tiles). o-proj..LN2 run wave-locally (in-register LN via shfl, wave-local
// LDS redistribution, no barriers). 6 barriers total. LDS 52992B -> 3 blocks/CU.

typedef __bf16 bhalf;
typedef __bf16 bhalf4 __attribute__((ext_vector_type(4)));
typedef __bf16 bhalf8 __attribute__((ext_vector_type(8)));
typedef float f32x4 __attribute__((ext_vector_type(4)));

#define DEV static __device__ __forceinline__

DEV f32x4 mfma16(bhalf8 a, bhalf8 b, f32x4 c) {
  return __builtin_amdgcn_mfma_f32_16x16x32_bf16(a, b, c, 0, 0, 0);
}

// ---------------- pointer bundle ----------------
struct Ptrs {
  const float* state;
  const float *p_in_w, *p_in_b, *p_qkv_b, *p_o_b, *p_g1, *p_b1, *p_ff1_b, *p_ff2_b, *p_g2, *p_b2, *p_out_b;
  const float *s_in_w, *s_in_b, *s_qkv_b, *s_o_b, *s_g1, *s_b1, *s_ff1_b, *s_ff2_b, *s_g2, *s_b2, *s_out_b;
  const float *e_w, *e_b, *d1_b, *d2_b, *pi_w, *pi_b, *v_w, *v_b;
  const bhalf *w_qkv, *w_o, *w_ff1, *w_ff2, *w_out;       // power
  const bhalf *w_qkv2, *w_o2, *w_ff12, *w_ff22, *w_out2;  // sword
  const bhalf *w_d1, *w_d2;
  float* out;
};

// ---------------- prep: fp32 -> bf16 weight conversion ----------------
struct PrepArgs {
  const float* src[12];
  int len[12];
  bhalf* dst;
};

__global__ void prep_bf16(PrepArgs a) {
  int idx = blockIdx.x * blockDim.x + threadIdx.x;
  int off = 0;
#pragma unroll
  for (int i = 0; i < 12; ++i) {
    int n = a.len[i];
    if (idx >= off && idx < off + n) a.dst[idx] = (bhalf)a.src[i][idx - off];
    off += n;
  }
}

// ---------------- attention: one (token a, sample s, head h) ----------------
template <int T>
DEV void attn_head(const bhalf* qkv, bhalf* obuf, int rowbase, int a, int s, int h) {
  const bhalf8 qv = *(const bhalf8*)&qkv[(rowbase + a * 16 + s) * 104 + h * 8];
  float q[8];
#pragma unroll
  for (int i = 0; i < 8; ++i) q[i] = (float)qv[i];
  float sc[T];
  float mx = -1e30f;
#pragma unroll
  for (int b = 0; b < T; ++b) {
    bhalf8 kv = *(const bhalf8*)&qkv[(rowbase + b * 16 + s) * 104 + 32 + h * 8];
    float d = 0.f;
#pragma unroll
    for (int i = 0; i < 8; ++i) d += q[i] * (float)kv[i];
    d *= 0.35355339059327378f;  // 1/sqrt(8)
    sc[b] = d;
    mx = fmaxf(mx, d);
  }
  float sum = 0.f;
#pragma unroll
  for (int b = 0; b < T; ++b) { sc[b] = __expf(sc[b] - mx); sum += sc[b]; }
  float inv = 1.f / sum;
  float o[8] = {0.f, 0.f, 0.f, 0.f, 0.f, 0.f, 0.f, 0.f};
#pragma unroll
  for (int b = 0; b < T; ++b) {
    bhalf8 vv = *(const bhalf8*)&qkv[(rowbase + b * 16 + s) * 104 + 64 + h * 8];
    float w = sc[b] * inv;
#pragma unroll
    for (int i = 0; i < 8; ++i) o[i] += w * (float)vv[i];
  }
  bhalf8 ov;
#pragma unroll
  for (int i = 0; i < 8; ++i) ov[i] = (bhalf)o[i];
  *(bhalf8*)&obuf[(rowbase + a * 16 + s) * 40 + h * 8] = ov;
}

// ---------------- main fused kernel ----------------
__launch_bounds__(576, 7)
__global__ void aac_main(Ptrs P) {
  // 52992 B total -> 3 blocks/CU
  __shared__ __align__(16) bhalf s_x[144 * 40];     // activations (power rows 0-111, sword 112-143)
  __shared__ __align__(16) bhalf s_qkv[144 * 104];  // qkv; later xcat[16][408] + h2[16][132]f32
  __shared__ __align__(16) bhalf s_o[144 * 40];     // attn-out / per-wave scratch; later h1[16][136]

  bhalf* xcat = s_qkv;                    // [16][408]
  float* h2 = (float*)(s_qkv + 16 * 408); // [16][132] (13056B offset, disjoint from xcat)
  bhalf* h1 = s_o;                        // [16][136]

  const int tid = threadIdx.x;
  const int wave = tid >> 6, lane = tid & 63;
  const int l15 = lane & 15, lq = lane >> 4;
  const int s0 = blockIdx.x * 16;

  // ---- input linears (K=2 power, K=4 sword), state read from global (L1) ----
  for (int i = tid; i < 112 * 32; i += 576) {
    int row = i >> 5, e = i & 31;
    int t = row >> 4, s = row & 15;
    const float* st = &P.state[(size_t)(s0 + s) * 30 + t * 2];
    float v = P.p_in_b[e] + P.p_in_w[e * 2] * st[0] + P.p_in_w[e * 2 + 1] * st[1];
    s_x[row * 40 + e] = (bhalf)v;
  }
  for (int i = tid; i < 32 * 32; i += 576) {
    int row = i >> 5, e = i & 31;
    int t = row >> 4, s = row & 15;
    const float* st = &P.state[(size_t)(s0 + s) * 30 + 14 + t * 4];
    float v = P.s_in_b[e];
#pragma unroll
    for (int j = 0; j < 4; ++j) v += P.s_in_w[e * 4 + j] * st[j];
    s_x[(112 + row) * 40 + e] = (bhalf)v;
  }
  __syncthreads();

  // ---- QKV: 9 M-tiles x 6 N-tiles, 6 per wave ----
  for (int f = wave; f < 54; f += 9) {
    int mt = f / 6, n = f - mt * 6;
    bool sw = mt >= 7;
    const bhalf* wq = sw ? P.w_qkv2 : P.w_qkv;
    const float* qb = sw ? P.s_qkv_b : P.p_qkv_b;
    bhalf8 a = *(const bhalf8*)&wq[(n * 16 + l15) * 32 + lq * 8];
    bhalf8 b = *(const bhalf8*)&s_x[(mt * 16 + l15) * 40 + lq * 8];
    f32x4 c = {0.f, 0.f, 0.f, 0.f};
    c = mfma16(a, b, c);
    int arow = mt * 16 + l15, oc0 = n * 16 + lq * 4;
    f32x4 bias = *(const f32x4*)&qb[oc0];
    bhalf4 o;
#pragma unroll
    for (int j = 0; j < 4; ++j) o[j] = (bhalf)(c[j] + bias[j]);
    *(bhalf4*)&s_qkv[arow * 104 + oc0] = o;
  }
  __syncthreads();

  // ---- attention: wave a handles token a (output rows == own M-tile) ----
  if (tid < 448) {
    attn_head<7>(s_qkv, s_o, 0, tid >> 6, (tid >> 2) & 15, tid & 3);
  } else {
    int idx = tid - 448;
    attn_head<2>(s_qkv, s_o, 112, idx >> 6, (idx >> 2) & 15, idx & 3);
  }
  // NO barrier: s_o writes are wave-local; phase D consumes own wave's rows.

  // ---- phase D (wave-local): o-proj -> LN1 -> FF1 -> FF2 -> LN2 ----
  {
    const int w = wave;
    const bool sw = w >= 7;
    const bhalf* wo = sw ? P.w_o2 : P.w_o;
    const bhalf* wf1 = sw ? P.w_ff12 : P.w_ff1;
    const bhalf* wf2 = sw ? P.w_ff22 : P.w_ff2;
    const float* ob = sw ? P.s_o_b : P.p_o_b;
    const float* g1 = sw ? P.s_g1 : P.p_g1;
    const float* b1 = sw ? P.s_b1 : P.p_b1;
    const float* f1b = sw ? P.s_ff1_b : P.p_ff1_b;
    const float* f2b = sw ? P.s_ff2_b : P.p_ff2_b;
    const float* g2 = sw ? P.s_g2 : P.p_g2;
    const float* b2 = sw ? P.s_b2 : P.p_b2;
    const int row = w * 16 + l15;
    const int oc0 = lq * 4;

    // o-projection (2 MFMA) + bias + residual
    bhalf8 bfrag = *(const bhalf8*)&s_o[row * 40 + lq * 8];
    f32x4 c0 = {0.f, 0.f, 0.f, 0.f}, c1 = {0.f, 0.f, 0.f, 0.f};
    c0 = mfma16(*(const bhalf8*)&wo[l15 * 32 + lq * 8], bfrag, c0);
    c1 = mfma16(*(const bhalf8*)&wo[(16 + l15) * 32 + lq * 8], bfrag, c1);
    f32x4 bb0 = *(const f32x4*)&ob[oc0], bb1 = *(const f32x4*)&ob[16 + oc0];
    bhalf4 r0 = *(const bhalf4*)&s_x[row * 40 + oc0];
    bhalf4 r1 = *(const bhalf4*)&s_x[row * 40 + 16 + oc0];
    float x[8];
#pragma unroll
    for (int j = 0; j < 4; ++j) {
      x[j] = c0[j] + bb0[j] + (float)r0[j];
      x[4 + j] = c1[j] + bb1[j] + (float)r1[j];
    }
    // LN1 in-register (row spread across lanes l15, l15+16, l15+32, l15+48)
    float sum = 0.f, ss = 0.f;
#pragma unroll
    for (int i = 0; i < 8; ++i) { sum += x[i]; ss += x[i] * x[i]; }
    sum += __shfl_xor(sum, 16); sum += __shfl_xor(sum, 32);
    ss += __shfl_xor(ss, 16); ss += __shfl_xor(ss, 32);
    float mu = sum * 0.03125f;
    float rs = rsqrtf(ss * 0.03125f - mu * mu + 1e-5f);
    f32x4 gg0 = *(const f32x4*)&g1[oc0], gg1 = *(const f32x4*)&g1[16 + oc0];
    f32x4 hb0 = *(const f32x4*)&b1[oc0], hb1 = *(const f32x4*)&b1[16 + oc0];
    float xn[8];
#pragma unroll
    for (int j = 0; j < 4; ++j) {
      xn[j] = (x[j] - mu) * rs * gg0[j] + hb0[j];
      xn[4 + j] = (x[4 + j] - mu) * rs * gg1[j] + hb1[j];
    }
    // redistribute C-layout -> B-frag via wave-local LDS scratch
    bhalf4 w0, w1;
#pragma unroll
    for (int j = 0; j < 4; ++j) { w0[j] = (bhalf)xn[j]; w1[j] = (bhalf)xn[4 + j]; }
    *(bhalf4*)&s_o[row * 40 + oc0] = w0;
    *(bhalf4*)&s_o[row * 40 + 16 + oc0] = w1;
    bfrag = *(const bhalf8*)&s_o[row * 40 + lq * 8];

    // FF1 (2 MFMA) + bias + relu
    c0 = f32x4{0.f, 0.f, 0.f, 0.f}; c1 = f32x4{0.f, 0.f, 0.f, 0.f};
    c0 = mfma16(*(const bhalf8*)&wf1[l15 * 32 + lq * 8], bfrag, c0);
    c1 = mfma16(*(const bhalf8*)&wf1[(16 + l15) * 32 + lq * 8], bfrag, c1);
    bb0 = *(const f32x4*)&f1b[oc0]; bb1 = *(const f32x4*)&f1b[16 + oc0];
#pragma unroll
    for (int j = 0; j < 4; ++j) {
      w0[j] = (bhalf)fmaxf(c0[j] + bb0[j], 0.f);
      w1[j] = (bhalf)fmaxf(c1[j] + bb1[j], 0.f);
    }
    *(bhalf4*)&s_o[row * 40 + oc0] = w0;
    *(bhalf4*)&s_o[row * 40 + 16 + oc0] = w1;
    bfrag = *(const bhalf8*)&s_o[row * 40 + lq * 8];

    // FF2 (2 MFMA) + bias + residual (f32 xn) -> LN2
    c0 = f32x4{0.f, 0.f, 0.f, 0.f}; c1 = f32x4{0.f, 0.f, 0.f, 0.f};
    c0 = mfma16(*(const bhalf8*)&wf2[l15 * 32 + lq * 8], bfrag, c0);
    c1 = mfma16(*(const bhalf8*)&wf2[(16 + l15) * 32 + lq * 8], bfrag, c1);
    bb0 = *(const f32x4*)&f2b[oc0]; bb1 = *(const f32x4*)&f2b[16 + oc0];
#pragma unroll
    for (int j = 0; j < 4; ++j) {
      x[j] = c0[j] + bb0[j] + xn[j];
      x[4 + j] = c1[j] + bb1[j] + xn[4 + j];
    }
    sum = 0.f; ss = 0.f;
#pragma unroll
    for (int i = 0; i < 8; ++i) { sum += x[i]; ss += x[i] * x[i]; }
    sum += __shfl_xor(sum, 16); sum += __shfl_xor(sum, 32);
    ss += __shfl_xor(ss, 16); ss += __shfl_xor(ss, 32);
    mu = sum * 0.03125f;
    rs = rsqrtf(ss * 0.03125f - mu * mu + 1e-5f);
    gg0 = *(const f32x4*)&g2[oc0]; gg1 = *(const f32x4*)&g2[16 + oc0];
    hb0 = *(const f32x4*)&b2[oc0]; hb1 = *(const f32x4*)&b2[16 + oc0];
#pragma unroll
    for (int j = 0; j < 4; ++j) {
      w0[j] = (bhalf)((x[j] - mu) * rs * gg0[j] + hb0[j]);
      w1[j] = (bhalf)((x[4 + j] - mu) * rs * gg1[j] + hb1[j]);
    }
    *(bhalf4*)&s_x[row * 40 + oc0] = w0;
    *(bhalf4*)&s_x[row * 40 + 16 + oc0] = w1;
  }
  __syncthreads();

  // ---- out_gemm (16 jobs over 9 waves) + st_emb -> xcat [16][408] ----
  for (int f = wave; f < 16; f += 9) {
    int br = f >> 3, n = f & 7;
    int T = br ? 2 : 7, rowbase = br ? 112 : 0, wst = br ? 64 : 224;
    const bhalf* wg = br ? P.w_out2 : P.w_out;
    const float* bb = br ? P.s_out_b : P.p_out_b;
    f32x4 c = {0.f, 0.f, 0.f, 0.f};
    for (int t = 0; t < T; ++t) {
      bhalf8 a = *(const bhalf8*)&wg[(n * 16 + l15) * wst + t * 32 + lq * 8];
      bhalf8 b = *(const bhalf8*)&s_x[(rowbase + t * 16 + l15) * 40 + lq * 8];
      c = mfma16(a, b, c);
    }
    int oc = n * 16 + lq * 4;
    f32x4 bias = *(const f32x4*)&bb[oc];
    bhalf4 o;
#pragma unroll
    for (int j = 0; j < 4; ++j) o[j] = (bhalf)fmaxf(c[j] + bias[j], 0.f);
    *(bhalf4*)&xcat[l15 * 408 + br * 128 + oc] = o;
  }
  for (int i = tid; i < 16 * 128; i += 576) {
    int s = i >> 7, col = i & 127;
    f32x4 w0 = *(const f32x4*)&P.e_w[col * 8];
    f32x4 w1 = *(const f32x4*)&P.e_w[col * 8 + 4];
    const float* st = &P.state[(size_t)(s0 + s) * 30 + 22];
    float v = P.e_b[col];
#pragma unroll
    for (int j = 0; j < 4; ++j) v += w0[j] * st[j] + w1[j] * st[4 + j];
    xcat[s * 408 + 256 + col] = (bhalf)fmaxf(v, 0.f);
  }
  __syncthreads();

  // ---- d1: [16,384] x [384,128] + relu -> h1 ----
  if (wave < 8) {
    int n = wave;
    f32x4 c = {0.f, 0.f, 0.f, 0.f};
#pragma unroll
    for (int ks = 0; ks < 12; ++ks) {
      bhalf8 a = *(const bhalf8*)&P.w_d1[(n * 16 + l15) * 384 + ks * 32 + lq * 8];
      bhalf8 b = *(const bhalf8*)&xcat[l15 * 408 + ks * 32 + lq * 8];
      c = mfma16(a, b, c);
    }
    int oc = n * 16 + lq * 4;
    f32x4 bias = *(const f32x4*)&P.d1_b[oc];
    bhalf4 o;
#pragma unroll
    for (int j = 0; j < 4; ++j) o[j] = (bhalf)fmaxf(c[j] + bias[j], 0.f);
    *(bhalf4*)&h1[l15 * 136 + oc] = o;
  }
  __syncthreads();

  // ---- d2: [16,128] x [128,128] + relu -> h2 (f32) ----
  if (wave < 8) {
    int n = wave;
    f32x4 c = {0.f, 0.f, 0.f, 0.f};
#pragma unroll
    for (int ks = 0; ks < 4; ++ks) {
      bhalf8 a = *(const bhalf8*)&P.w_d2[(n * 16 + l15) * 128 + ks * 32 + lq * 8];
      bhalf8 b = *(const bhalf8*)&h1[l15 * 136 + ks * 32 + lq * 8];
      c = mfma16(a, b, c);
    }
    int oc = n * 16 + lq * 4;
    f32x4 bias = *(const f32x4*)&P.d2_b[oc];
    f32x4 o;
#pragma unroll
    for (int j = 0; j < 4; ++j) o[j] = fmaxf(c[j] + bias[j], 0.f);
    *(f32x4*)&h2[l15 * 132 + oc] = o;
  }
  __syncthreads();

  // ---- heads: 4 lanes per (sample, output); softmax over o via shfl ----
  if (tid < 512) {
    int s = tid >> 5, o = (tid >> 2) & 7, q = tid & 3;
    const float* wrow = (o < 7) ? &P.pi_w[o * 128 + q * 32] : &P.v_w[q * 32];
    const float* hrow = &h2[s * 132 + q * 32];
    float acc = 0.f;
#pragma unroll
    for (int k = 0; k < 8; ++k) {
      f32x4 wv = *(const f32x4*)&wrow[k * 4];
      f32x4 hv = *(const f32x4*)&hrow[k * 4];
#pragma unroll
      for (int j = 0; j < 4; ++j) acc += wv[j] * hv[j];
    }
    acc += __shfl_xor(acc, 1);
    acc += __shfl_xor(acc, 2);
    acc += (o < 7) ? P.pi_b[o] : P.v_b[0];
    float xm = (o < 7) ? acc : -1e30f;
#pragma unroll
    for (int m = 4; m < 32; m <<= 1) xm = fmaxf(xm, __shfl_xor(xm, m));
    float e = (o < 7) ? __expf(acc - xm) : 0.f;
    float se = e;
#pragma unroll
    for (int m = 4; m < 32; m <<= 1) se += __shfl_xor(se, m);
    if (q == 0) {
      if (o < 7) P.out[(size_t)(s0 + s) * 7 + o] = e / se;
      else       P.out[917504 + s0 + s] = acc;  // 131072*7
    }
  }
}

// ---------------- launch ----------------
extern "C" void kernel_launch(void* const* d_in, const int* in_sizes, int n_in,
                              void* d_out, int out_size, void* d_ws, size_t ws_size,
                              hipStream_t stream) {
  (void)in_sizes; (void)n_in; (void)out_size; (void)ws_size;
  const float* const* in = (const float* const*)d_in;
  bhalf* wbf = (bhalf*)d_ws;

  PrepArgs pa;
  const int srcIdx[12] = {3, 5, 9, 11, 15, 19, 21, 25, 27, 31, 35, 37};
  const int lens[12] = {3072, 1024, 1024, 1024, 28672, 3072, 1024, 1024, 1024, 8192, 49152, 16384};
  for (int i = 0; i < 12; ++i) { pa.src[i] = in[srcIdx[i]]; pa.len[i] = lens[i]; }
  pa.dst = wbf;
  hipLaunchKernelGGL(prep_bf16, dim3(448), dim3(256), 0, stream, pa);

  Ptrs P;
  P.state = in[0];
  P.p_in_w = in[1];  P.p_in_b = in[2];  P.p_qkv_b = in[4];  P.p_o_b = in[6];
  P.p_g1 = in[7];    P.p_b1 = in[8];    P.p_ff1_b = in[10]; P.p_ff2_b = in[12];
  P.p_g2 = in[13];   P.p_b2 = in[14];   P.p_out_b = in[16];
  P.s_in_w = in[17]; P.s_in_b = in[18]; P.s_qkv_b = in[20]; P.s_o_b = in[22];
  P.s_g1 = in[23];   P.s_b1 = in[24];   P.s_ff1_b = in[26]; P.s_ff2_b = in[28];
  P.s_g2 = in[29];   P.s_b2 = in[30];   P.s_out_b = in[32];
  P.e_w = in[33];    P.e_b = in[34];    P.d1_b = in[36];    P.d2_b = in[38];
  P.pi_w = in[39];   P.pi_b = in[40];   P.v_w = in[41];     P.v_b = in[42];
  P.w_qkv = wbf;             P.w_o = wbf + 3072;    P.w_ff1 = wbf + 4096;
  P.w_ff2 = wbf + 5120;      P.w_out = wbf + 6144;
  P.w_qkv2 = wbf + 34816;    P.w_o2 = wbf + 37888;  P.w_ff12 = wbf + 38912;
  P.w_ff22 = wbf + 39936;    P.w_out2 = wbf + 40960;
  P.w_d1 = wbf + 49152;      P.w_d2 = wbf + 98304;
  P.out = (float*)d_out;

  hipLaunchKernelGGL(aac_main, dim3(8192), dim3(576), 0, stream, P);  // 131072/16 blocks
}

// Round 4
// 374.527 us; speedup vs baseline: 1.1127x; 1.1127x over previous
//
#include <hip/hip_runtime.h>

// AttentionActorCritic fused forward, MI355X (gfx950).
// Round 4: r2 bulk-phase skeleton + LDS diet (52992B -> 3 blocks/CU, 8-wave
// blocks) + batched K/V register preload in attention + bf16 residual scratch
// aliased into dead s_qkv region. launch_bounds(512,6) for 6 waves/SIMD.

typedef __bf16 bhalf;
typedef __bf16 bhalf4 __attribute__((ext_vector_type(4)));
typedef __bf16 bhalf8 __attribute__((ext_vector_type(8)));
typedef float f32x4 __attribute__((ext_vector_type(4)));

#define DEV static __device__ __forceinline__

DEV f32x4 mfma16(bhalf8 a, bhalf8 b, f32x4 c) {
  return __builtin_amdgcn_mfma_f32_16x16x32_bf16(a, b, c, 0, 0, 0);
}

// ---------------- pointer bundle ----------------
struct Ptrs {
  const float* state;
  const float *p_in_w, *p_in_b, *p_qkv_b, *p_o_b, *p_g1, *p_b1, *p_ff1_b, *p_ff2_b, *p_g2, *p_b2, *p_out_b;
  const float *s_in_w, *s_in_b, *s_qkv_b, *s_o_b, *s_g1, *s_b1, *s_ff1_b, *s_ff2_b, *s_g2, *s_b2, *s_out_b;
  const float *e_w, *e_b, *d1_b, *d2_b, *pi_w, *pi_b, *v_w, *v_b;
  const bhalf *w_qkv, *w_o, *w_ff1, *w_ff2, *w_out;       // power
  const bhalf *w_qkv2, *w_o2, *w_ff12, *w_ff22, *w_out2;  // sword
  const bhalf *w_d1, *w_d2;
  float* out;
};

// ---------------- prep: fp32 -> bf16 weight conversion ----------------
struct PrepArgs {
  const float* src[12];
  int len[12];
  bhalf* dst;
};

__global__ void prep_bf16(PrepArgs a) {
  int idx = blockIdx.x * blockDim.x + threadIdx.x;
  int off = 0;
#pragma unroll
  for (int i = 0; i < 12; ++i) {
    int n = a.len[i];
    if (idx >= off && idx < off + n) a.dst[idx] = (bhalf)a.src[i][idx - off];
    off += n;
  }
}

// ---------------- attention: one (token a, sample s, head h) ----------------
// K fragments batch-preloaded before score loop; V batch-preloaded before PV.
template <int T>
DEV void attn_head(const bhalf* qkv, bhalf* obuf, int rowbase, int a, int s, int h) {
  const bhalf* base = &qkv[(rowbase + s) * 104 + h * 8];
  const int rstep = 16 * 104;
  bhalf8 kf[T];
#pragma unroll
  for (int b = 0; b < T; ++b) kf[b] = *(const bhalf8*)(base + b * rstep + 32);
  bhalf8 qv = *(const bhalf8*)(base + a * rstep);
  float q[8];
#pragma unroll
  for (int i = 0; i < 8; ++i) q[i] = (float)qv[i];
  float sc[T];
  float mx = -1e30f;
#pragma unroll
  for (int b = 0; b < T; ++b) {
    float d = 0.f;
#pragma unroll
    for (int i = 0; i < 8; ++i) d += q[i] * (float)kf[b][i];
    d *= 0.35355339059327378f;  // 1/sqrt(8)
    sc[b] = d;
    mx = fmaxf(mx, d);
  }
  bhalf8 vf[T];
#pragma unroll
  for (int b = 0; b < T; ++b) vf[b] = *(const bhalf8*)(base + b * rstep + 64);
  float sum = 0.f;
#pragma unroll
  for (int b = 0; b < T; ++b) { sc[b] = __expf(sc[b] - mx); sum += sc[b]; }
  float inv = 1.f / sum;
  float o[8] = {0.f, 0.f, 0.f, 0.f, 0.f, 0.f, 0.f, 0.f};
#pragma unroll
  for (int b = 0; b < T; ++b) {
    float w = sc[b] * inv;
#pragma unroll
    for (int i = 0; i < 8; ++i) o[i] += w * (float)vf[b][i];
  }
  bhalf8 ov;
#pragma unroll
  for (int i = 0; i < 8; ++i) ov[i] = (bhalf)o[i];
  *(bhalf8*)&obuf[(rowbase + a * 16 + s) * 40 + h * 8] = ov;
}

// ---------------- LayerNorm pass: tmp(bf16) -> xb(bf16), 2 threads/row ----------------
DEV void ln_pass(int tid, const bhalf* tmp, bhalf* xb,
                 const float* gp, const float* bp, const float* gs, const float* bs) {
  if (tid < 288) {
    int row = tid >> 1, half = tid & 1;
    bhalf8 a0 = *(const bhalf8*)&tmp[row * 40 + half * 16];
    bhalf8 a1 = *(const bhalf8*)&tmp[row * 40 + half * 16 + 8];
    float v[16];
#pragma unroll
    for (int i = 0; i < 8; ++i) { v[i] = (float)a0[i]; v[8 + i] = (float)a1[i]; }
    float sum = 0.f, ss = 0.f;
#pragma unroll
    for (int i = 0; i < 16; ++i) { sum += v[i]; ss += v[i] * v[i]; }
    sum += __shfl_xor(sum, 1);
    ss += __shfl_xor(ss, 1);
    float mu = sum * 0.03125f;
    float rs = rsqrtf(ss * 0.03125f - mu * mu + 1e-5f);
    const float* g = (row < 112) ? gp : gs;
    const float* b = (row < 112) ? bp : bs;
    bhalf8 o0, o1;
#pragma unroll
    for (int i = 0; i < 8; ++i) {
      o0[i] = (bhalf)((v[i] - mu) * rs * g[half * 16 + i] + b[half * 16 + i]);
      o1[i] = (bhalf)((v[8 + i] - mu) * rs * g[half * 16 + 8 + i] + b[half * 16 + 8 + i]);
    }
    *(bhalf8*)&xb[row * 40 + half * 16] = o0;
    *(bhalf8*)&xb[row * 40 + half * 16 + 8] = o1;
  }
}

// ---------------- main fused kernel ----------------
__launch_bounds__(512, 6)
__global__ void aac_main(Ptrs P) {
  // 52992 B total -> 3 blocks/CU
  __shared__ __align__(16) bhalf s_x[144 * 40];     // 11520B: activations
  __shared__ __align__(16) bhalf s_qkv[144 * 104];  // 29952B: qkv; aliased: tmp[144][40], xcat[16][408], h2[16][132]f32
  __shared__ __align__(16) bhalf s_o[144 * 40];     // 11520B: attn-out/ff1; aliased: h1[16][136]

  bhalf* tmp = s_qkv;                      // [144][40] bf16 residual scratch
  bhalf* xcat = s_qkv;                     // [16][408]
  float* h2 = (float*)(s_qkv + 16 * 408);  // [16][132] f32, elems 6528..10751 (disjoint from xcat)
  bhalf* h1 = s_o;                         // [16][136]

  const int tid = threadIdx.x;
  const int wave = tid >> 6, lane = tid & 63;
  const int l15 = lane & 15, lq = lane >> 4;
  const int s0 = blockIdx.x * 16;

  // ---- input linears (K=2 power, K=4 sword), state from global/L1 ----
  for (int i = tid; i < 112 * 32; i += 512) {
    int row = i >> 5, e = i & 31;
    int t = row >> 4, s = row & 15;
    const float* st = &P.state[(size_t)(s0 + s) * 30 + t * 2];
    float v = P.p_in_b[e] + P.p_in_w[e * 2] * st[0] + P.p_in_w[e * 2 + 1] * st[1];
    s_x[row * 40 + e] = (bhalf)v;
  }
  for (int i = tid; i < 32 * 32; i += 512) {
    int row = i >> 5, e = i & 31;
    int t = row >> 4, s = row & 15;
    const float* st = &P.state[(size_t)(s0 + s) * 30 + 14 + t * 4];
    float v = P.s_in_b[e];
#pragma unroll
    for (int j = 0; j < 4; ++j) v += P.s_in_w[e * 4 + j] * st[j];
    s_x[(112 + row) * 40 + e] = (bhalf)v;
  }
  __syncthreads();

  // ---- QKV: 9 M-tiles x 6 N-tiles ----
  for (int f = wave; f < 54; f += 8) {
    int mt = f / 6, n = f - mt * 6;
    bool sw = mt >= 7;
    const bhalf* wq = sw ? P.w_qkv2 : P.w_qkv;
    const float* qb = sw ? P.s_qkv_b : P.p_qkv_b;
    bhalf8 a = *(const bhalf8*)&wq[(n * 16 + l15) * 32 + lq * 8];
    bhalf8 b = *(const bhalf8*)&s_x[(mt * 16 + l15) * 40 + lq * 8];
    f32x4 c = {0.f, 0.f, 0.f, 0.f};
    c = mfma16(a, b, c);
    int arow = mt * 16 + l15, oc0 = n * 16 + lq * 4;
    f32x4 bias = *(const f32x4*)&qb[oc0];
    bhalf4 o;
#pragma unroll
    for (int j = 0; j < 4; ++j) o[j] = (bhalf)(c[j] + bias[j]);
    *(bhalf4*)&s_qkv[arow * 104 + oc0] = o;
  }
  __syncthreads();

  // ---- attention: power waves 0-6 (token = wave), wave 7 sword ----
  if (tid < 448) {
    attn_head<7>(s_qkv, s_o, 0, tid >> 6, (tid >> 2) & 15, tid & 3);
  } else {
    int idx = tid - 448;
    attn_head<2>(s_qkv, s_o, 112, 0, (idx >> 2) & 15, idx & 3);
    attn_head<2>(s_qkv, s_o, 112, 1, (idx >> 2) & 15, idx & 3);
  }
  __syncthreads();

  // ---- o-projection + residual -> tmp (bf16, aliases dead s_qkv) ----
  for (int f = wave; f < 18; f += 8) {
    int mt = f >> 1, n = f & 1;
    bool sw = mt >= 7;
    const bhalf* wo = sw ? P.w_o2 : P.w_o;
    const float* ob = sw ? P.s_o_b : P.p_o_b;
    bhalf8 a = *(const bhalf8*)&wo[(n * 16 + l15) * 32 + lq * 8];
    bhalf8 b = *(const bhalf8*)&s_o[(mt * 16 + l15) * 40 + lq * 8];
    f32x4 c = {0.f, 0.f, 0.f, 0.f};
    c = mfma16(a, b, c);
    int arow = mt * 16 + l15, oc0 = n * 16 + lq * 4;
    f32x4 bias = *(const f32x4*)&ob[oc0];
    bhalf4 res = *(const bhalf4*)&s_x[arow * 40 + oc0];
    bhalf4 o;
#pragma unroll
    for (int j = 0; j < 4; ++j) o[j] = (bhalf)(c[j] + bias[j] + (float)res[j]);
    *(bhalf4*)&tmp[arow * 40 + oc0] = o;
  }
  __syncthreads();

  // ---- LN1: tmp -> s_x ----
  ln_pass(tid, tmp, s_x, P.p_g1, P.p_b1, P.s_g1, P.s_b1);
  __syncthreads();

  // ---- FF1 + relu -> s_o ----
  for (int f = wave; f < 18; f += 8) {
    int mt = f >> 1, n = f & 1;
    bool sw = mt >= 7;
    const bhalf* wf = sw ? P.w_ff12 : P.w_ff1;
    const float* fb = sw ? P.s_ff1_b : P.p_ff1_b;
    bhalf8 a = *(const bhalf8*)&wf[(n * 16 + l15) * 32 + lq * 8];
    bhalf8 b = *(const bhalf8*)&s_x[(mt * 16 + l15) * 40 + lq * 8];
    f32x4 c = {0.f, 0.f, 0.f, 0.f};
    c = mfma16(a, b, c);
    int arow = mt * 16 + l15, oc0 = n * 16 + lq * 4;
    f32x4 bias = *(const f32x4*)&fb[oc0];
    bhalf4 o;
#pragma unroll
    for (int j = 0; j < 4; ++j) o[j] = (bhalf)fmaxf(c[j] + bias[j], 0.f);
    *(bhalf4*)&s_o[arow * 40 + oc0] = o;
  }
  __syncthreads();

  // ---- FF2 + residual -> tmp ----
  for (int f = wave; f < 18; f += 8) {
    int mt = f >> 1, n = f & 1;
    bool sw = mt >= 7;
    const bhalf* wf = sw ? P.w_ff22 : P.w_ff2;
    const float* fb = sw ? P.s_ff2_b : P.p_ff2_b;
    bhalf8 a = *(const bhalf8*)&wf[(n * 16 + l15) * 32 + lq * 8];
    bhalf8 b = *(const bhalf8*)&s_o[(mt * 16 + l15) * 40 + lq * 8];
    f32x4 c = {0.f, 0.f, 0.f, 0.f};
    c = mfma16(a, b, c);
    int arow = mt * 16 + l15, oc0 = n * 16 + lq * 4;
    f32x4 bias = *(const f32x4*)&fb[oc0];
    bhalf4 res = *(const bhalf4*)&s_x[arow * 40 + oc0];
    bhalf4 o;
#pragma unroll
    for (int j = 0; j < 4; ++j) o[j] = (bhalf)(c[j] + bias[j] + (float)res[j]);
    *(bhalf4*)&tmp[arow * 40 + oc0] = o;
  }
  __syncthreads();

  // ---- LN2: tmp -> s_x ----
  ln_pass(tid, tmp, s_x, P.p_g2, P.p_b2, P.s_g2, P.s_b2);
  __syncthreads();

  // ---- out_gemm (16 jobs / 8 waves) + st_emb -> xcat [16][408] ----
  for (int f = wave; f < 16; f += 8) {
    int br = f >> 3, n = f & 7;
    int T = br ? 2 : 7, rowbase = br ? 112 : 0, wst = br ? 64 : 224;
    const bhalf* wg = br ? P.w_out2 : P.w_out;
    const float* bb = br ? P.s_out_b : P.p_out_b;
    f32x4 c = {0.f, 0.f, 0.f, 0.f};
    for (int t = 0; t < T; ++t) {
      bhalf8 a = *(const bhalf8*)&wg[(n * 16 + l15) * wst + t * 32 + lq * 8];
      bhalf8 b = *(const bhalf8*)&s_x[(rowbase + t * 16 + l15) * 40 + lq * 8];
      c = mfma16(a, b, c);
    }
    int oc = n * 16 + lq * 4;
    f32x4 bias = *(const f32x4*)&bb[oc];
    bhalf4 o;
#pragma unroll
    for (int j = 0; j < 4; ++j) o[j] = (bhalf)fmaxf(c[j] + bias[j], 0.f);
    *(bhalf4*)&xcat[l15 * 408 + br * 128 + oc] = o;
  }
  for (int i = tid; i < 16 * 128; i += 512) {
    int s = i >> 7, col = i & 127;
    f32x4 w0 = *(const f32x4*)&P.e_w[col * 8];
    f32x4 w1 = *(const f32x4*)&P.e_w[col * 8 + 4];
    const float* st = &P.state[(size_t)(s0 + s) * 30 + 22];
    float v = P.e_b[col];
#pragma unroll
    for (int j = 0; j < 4; ++j) v += w0[j] * st[j] + w1[j] * st[4 + j];
    xcat[s * 408 + 256 + col] = (bhalf)fmaxf(v, 0.f);
  }
  __syncthreads();

  // ---- d1: [16,384] x [384,128] + relu -> h1 (disjoint buffer, no pre-barrier) ----
  {
    int n = wave;
    f32x4 c = {0.f, 0.f, 0.f, 0.f};
#pragma unroll
    for (int ks = 0; ks < 12; ++ks) {
      bhalf8 a = *(const bhalf8*)&P.w_d1[(n * 16 + l15) * 384 + ks * 32 + lq * 8];
      bhalf8 b = *(const bhalf8*)&xcat[l15 * 408 + ks * 32 + lq * 8];
      c = mfma16(a, b, c);
    }
    int oc = n * 16 + lq * 4;
    f32x4 bias = *(const f32x4*)&P.d1_b[oc];
    bhalf4 o;
#pragma unroll
    for (int j = 0; j < 4; ++j) o[j] = (bhalf)fmaxf(c[j] + bias[j], 0.f);
    *(bhalf4*)&h1[l15 * 136 + oc] = o;
  }
  __syncthreads();

  // ---- d2: [16,128] x [128,128] + relu -> h2 (f32) ----
  {
    int n = wave;
    f32x4 c = {0.f, 0.f, 0.f, 0.f};
#pragma unroll
    for (int ks = 0; ks < 4; ++ks) {
      bhalf8 a = *(const bhalf8*)&P.w_d2[(n * 16 + l15) * 128 + ks * 32 + lq * 8];
      bhalf8 b = *(const bhalf8*)&h1[l15 * 136 + ks * 32 + lq * 8];
      c = mfma16(a, b, c);
    }
    int oc = n * 16 + lq * 4;
    f32x4 bias = *(const f32x4*)&P.d2_b[oc];
    f32x4 o;
#pragma unroll
    for (int j = 0; j < 4; ++j) o[j] = fmaxf(c[j] + bias[j], 0.f);
    *(f32x4*)&h2[l15 * 132 + oc] = o;
  }
  __syncthreads();

  // ---- heads: 4 lanes per (sample, output); softmax over o via shfl ----
  {
    int s = tid >> 5, o = (tid >> 2) & 7, q = tid & 3;
    const float* wrow = (o < 7) ? &P.pi_w[o * 128 + q * 32] : &P.v_w[q * 32];
    const float* hrow = &h2[s * 132 + q * 32];
    float acc = 0.f;
#pragma unroll
    for (int k = 0; k < 8; ++k) {
      f32x4 wv = *(const f32x4*)&wrow[k * 4];
      f32x4 hv = *(const f32x4*)&hrow[k * 4];
#pragma unroll
      for (int j = 0; j < 4; ++j) acc += wv[j] * hv[j];
    }
    acc += __shfl_xor(acc, 1);
    acc += __shfl_xor(acc, 2);
    acc += (o < 7) ? P.pi_b[o] : P.v_b[0];
    float xm = (o < 7) ? acc : -1e30f;
#pragma unroll
    for (int m = 4; m < 32; m <<= 1) xm = fmaxf(xm, __shfl_xor(xm, m));
    float e = (o < 7) ? __expf(acc - xm) : 0.f;
    float se = e;
#pragma unroll
    for (int m = 4; m < 32; m <<= 1) se += __shfl_xor(se, m);
    if (q == 0) {
      if (o < 7) P.out[(size_t)(s0 + s) * 7 + o] = e / se;
      else       P.out[917504 + s0 + s] = acc;  // 131072*7
    }
  }
}

// ---------------- launch ----------------
extern "C" void kernel_launch(void* const* d_in, const int* in_sizes, int n_in,
                              void* d_out, int out_size, void* d_ws, size_t ws_size,
                              hipStream_t stream) {
  (void)in_sizes; (void)n_in; (void)out_size; (void)ws_size;
  const float* const* in = (const float* const*)d_in;
  bhalf* wbf = (bhalf*)d_ws;

  PrepArgs pa;
  const int srcIdx[12] = {3, 5, 9, 11, 15, 19, 21, 25, 27, 31, 35, 37};
  const int lens[12] = {3072, 1024, 1024, 1024, 28672, 3072, 1024, 1024, 1024, 8192, 49152, 16384};
  for (int i = 0; i < 12; ++i) { pa.src[i] = in[srcIdx[i]]; pa.len[i] = lens[i]; }
  pa.dst = wbf;
  hipLaunchKernelGGL(prep_bf16, dim3(448), dim3(256), 0, stream, pa);

  Ptrs P;
  P.state = in[0];
  P.p_in_w = in[1];  P.p_in_b = in[2];  P.p_qkv_b = in[4];  P.p_o_b = in[6];
  P.p_g1 = in[7];    P.p_b1 = in[8];    P.p_ff1_b = in[10]; P.p_ff2_b = in[12];
  P.p_g2 = in[13];   P.p_b2 = in[14];   P.p_out_b = in[16];
  P.s_in_w = in[17]; P.s_in_b = in[18]; P.s_qkv_b = in[20]; P.s_o_b = in[22];
  P.s_g1 = in[23];   P.s_b1 = in[24];   P.s_ff1_b = in[26]; P.s_ff2_b = in[28];
  P.s_g2 = in[29];   P.s_b2 = in[30];   P.s_out_b = in[32];
  P.e_w = in[33];    P.e_b = in[34];    P.d1_b = in[36];    P.d2_b = in[38];
  P.pi_w = in[39];   P.pi_b = in[40];   P.v_w = in[41];     P.v_b = in[42];
  P.w_qkv = wbf;             P.w_o = wbf + 3072;    P.w_ff1 = wbf + 4096;
  P.w_ff2 = wbf + 5120;      P.w_out = wbf + 6144;
  P.w_qkv2 = wbf + 34816;    P.w_o2 = wbf + 37888;  P.w_ff12 = wbf + 38912;
  P.w_ff22 = wbf + 39936;    P.w_out2 = wbf + 40960;
  P.w_d1 = wbf + 49152;      P.w_d2 = wbf + 98304;
  P.out = (float*)d_out;

  hipLaunchKernelGGL(aac_main, dim3(8192), dim3(512), 0, stream, P);  // 131072/16 blocks
}